// Round 1
// baseline (766.965 us; speedup 1.0000x reference)
//
#include <hip/hip_runtime.h>

// HomologicalConnectivityLoss: adj (8192x8192 fp32, bit-exact symmetric).
// loss = (n_comp-1)^2 + max(0, n_edges - N + n_comp)^2
//   n_edges = count(adj>0) // 2  (full matrix incl. diagonal)
//   n_comp  = connected components of graph {(i,j): adj[i][j]>0}
//
// Strategy: single streaming pass over the LOWER TRIANGLE + diagonal only
// (matrix is bit-exact symmetric: (x+x^T)*0.5 commutes elementwise), with a
// fused lock-free union-find (atomicCAS hooking to the smaller-index root +
// path halving). n_comp = number of union-find roots afterwards.

#define NN 8192

// Agent-scope atomic load/store: parent[] is mutated by device-scope atomics
// from other CUs; plain loads could hit stale per-CU L1 (G16 hazard).
__device__ __forceinline__ int ld_parent(int* p, int i) {
    return __hip_atomic_load(&p[i], __ATOMIC_RELAXED, __HIP_MEMORY_SCOPE_AGENT);
}
__device__ __forceinline__ void st_parent(int* p, int i, int v) {
    __hip_atomic_store(&p[i], v, __ATOMIC_RELAXED, __HIP_MEMORY_SCOPE_AGENT);
}

// Path-halving find. Invariant: parent[x] <= x always (hooks go hi->lo),
// so chains strictly decrease -> always terminates, no cycles.
__device__ int find_root(int* parent, int x) {
    int p = ld_parent(parent, x);
    while (p != x) {
        int gp = ld_parent(parent, p);
        if (gp == p) return p;
        st_parent(parent, x, gp);   // shortcut to an ancestor (safe race)
        x = gp;
        p = ld_parent(parent, x);
    }
    return x;
}

// Lock-free union (ECL-CC style): hook larger root onto smaller via CAS.
__device__ void unite(int* parent, int a, int b) {
    int ra = find_root(parent, a);
    int rb = find_root(parent, b);
    while (ra != rb) {
        int hi = ra > rb ? ra : rb;
        int lo = ra > rb ? rb : ra;
        int prev = atomicCAS(&parent[hi], hi, lo);
        if (prev == hi) return;          // we performed the hook
        ra = find_root(parent, prev);    // someone else hooked hi; retry
        rb = find_root(parent, lo);
    }
}

__global__ __launch_bounds__(256) void init_kernel(int* parent, int* counters) {
    int i = blockIdx.x * 256 + threadIdx.x;
    if (i < NN) parent[i] = i;
    if (i < 2) counters[i] = 0;   // [0]=strict-lower positives, [1]=diag positives
}

// Block b processes rows b and NN-1-b (columns 0..r inclusive) -> every block
// touches ~NN+2 elements: perfect load balance. float4 coalesced reads; row
// base is 32KB-aligned so float4 alignment holds.
__global__ __launch_bounds__(256) void scan_kernel(const float* __restrict__ adj,
                                                   int* parent,
                                                   int* counters) {
    int b = blockIdx.x;
    int c2 = 0;  // strict lower-triangle positives (each = 2 in full-matrix count)
    int c1 = 0;  // diagonal positives
    #pragma unroll
    for (int half = 0; half < 2; ++half) {
        int r = half ? (NN - 1 - b) : b;
        const float4* rowp = (const float4*)(adj + (size_t)r * NN);
        int nf4 = (r + 4) >> 2;              // ceil((r+1)/4) float4 groups
        for (int g = threadIdx.x; g < nf4; g += 256) {
            float4 v = rowp[g];
            int j0 = g << 2;
            float vv[4] = {v.x, v.y, v.z, v.w};
            #pragma unroll
            for (int c = 0; c < 4; ++c) {
                int j = j0 + c;
                bool pos = vv[c] > 0.0f;
                if (j < r) {
                    if (pos) { c2++; unite(parent, r, j); }
                } else if (j == r) {
                    if (pos) c1++;
                }
            }
        }
    }
    // wave64 reduce, then one atomic per wave
    #pragma unroll
    for (int off = 32; off > 0; off >>= 1) {
        c2 += __shfl_down(c2, off, 64);
        c1 += __shfl_down(c1, off, 64);
    }
    if ((threadIdx.x & 63) == 0) {
        if (c2) atomicAdd(&counters[0], c2);
        if (c1) atomicAdd(&counters[1], c1);
    }
}

__global__ __launch_bounds__(1024) void final_kernel(const int* __restrict__ parent,
                                                     const int* __restrict__ counters,
                                                     float* __restrict__ out) {
    __shared__ int wsum[16];
    int cnt = 0;
    for (int i = threadIdx.x; i < NN; i += 1024)
        cnt += (parent[i] == i) ? 1 : 0;
    #pragma unroll
    for (int off = 32; off > 0; off >>= 1) cnt += __shfl_down(cnt, off, 64);
    if ((threadIdx.x & 63) == 0) wsum[threadIdx.x >> 6] = cnt;
    __syncthreads();
    if (threadIdx.x == 0) {
        int roots = 0;
        #pragma unroll
        for (int w = 0; w < 16; ++w) roots += wsum[w];
        long long total = 2LL * (long long)counters[0] + (long long)counters[1];
        long long n_edges_i = total >> 1;               // integer // 2, exact
        double n_comp = (double)roots;
        double comp_loss = (n_comp - 1.0) * (n_comp - 1.0);
        double betti = (double)n_edges_i - (double)NN + n_comp;
        double cyc = betti > 0.0 ? betti : 0.0;
        out[0] = (float)(comp_loss + cyc * cyc);
    }
}

extern "C" void kernel_launch(void* const* d_in, const int* in_sizes, int n_in,
                              void* d_out, int out_size, void* d_ws, size_t ws_size,
                              hipStream_t stream) {
    const float* adj = (const float*)d_in[0];
    int* parent = (int*)d_ws;           // 8192 ints
    int* counters = parent + NN;        // 2 ints
    float* out = (float*)d_out;

    init_kernel<<<NN / 256, 256, 0, stream>>>(parent, counters);
    scan_kernel<<<NN / 2, 256, 0, stream>>>(adj, parent, counters);
    final_kernel<<<1, 1024, 0, stream>>>(parent, counters, out);
}